// Round 4
// baseline (336.422 us; speedup 1.0000x reference)
//
#include <hip/hip_runtime.h>

#define T_SEQ 2048
#define D_MODEL 1024
#define NHEADS 16
#define HSZ 64
#define BATCH 4

typedef __bf16 bf16x8 __attribute__((ext_vector_type(8)));
typedef __bf16 bf16x4 __attribute__((ext_vector_type(4)));
typedef short short4v __attribute__((ext_vector_type(4)));
typedef float f32x4 __attribute__((ext_vector_type(4)));

__device__ __forceinline__ unsigned short f2bf(float f) {
    unsigned int u = __builtin_bit_cast(unsigned int, f);
    u += 0x7fff + ((u >> 16) & 1);   // RNE
    return (unsigned short)(u >> 16);
}

// pack two fp32 -> two bf16 (RNE) in one reg
__device__ __forceinline__ unsigned int pk2bf(float a, float b) {
#if __has_builtin(__builtin_amdgcn_cvt_pk_bf16_f32)
    typedef __bf16 bf16x2_t __attribute__((ext_vector_type(2)));
    bf16x2_t v = __builtin_amdgcn_cvt_pk_bf16_f32(a, b);
    return __builtin_bit_cast(unsigned int, v);
#else
    return (unsigned int)f2bf(a) | ((unsigned int)f2bf(b) << 16);
#endif
}

// K=16 bf16 MFMA: D[m][n] += sum_k A[m][k]B[k][n]; per-lane k = quad*4+j
__device__ __forceinline__ f32x4 mfma16_bf16(short4v a, short4v b, f32x4 c) {
#if __has_builtin(__builtin_amdgcn_mfma_f32_16x16x16_bf16)
    return __builtin_amdgcn_mfma_f32_16x16x16_bf16(
        __builtin_bit_cast(bf16x4, a), __builtin_bit_cast(bf16x4, b), c, 0, 0, 0);
#elif __has_builtin(__builtin_amdgcn_mfma_f32_16x16x16bf16_1k)
    return __builtin_amdgcn_mfma_f32_16x16x16bf16_1k(a, b, c, 0, 0, 0);
#else
    f32x4 d;
    asm volatile("v_mfma_f32_16x16x16_bf16 %0, %1, %2, %3"
                 : "=v"(d) : "v"(a), "v"(b), "v"(c));
    return d;
#endif
}

__device__ __forceinline__ void gld_lds16(const void* g, void* lds) {
    __builtin_amdgcn_global_load_lds(
        (const __attribute__((address_space(1))) unsigned int*)g,
        (__attribute__((address_space(3))) unsigned int*)lds, 16, 0, 0);
}

__device__ __forceinline__ bf16x8 ld8(const unsigned short* p) {
    return *(const bf16x8*)p;
}

// ---------------- casts ----------------
__global__ void cast_x(const float* __restrict__ src, unsigned short* __restrict__ dst, int n4) {
    int i = blockIdx.x * blockDim.x + threadIdx.x;
    if (i >= n4) return;
    float4 v = ((const float4*)src)[i];
    ushort4 o;
    o.x = f2bf(v.x); o.y = f2bf(v.y); o.z = f2bf(v.z); o.w = f2bf(v.w);
    ((ushort4*)dst)[i] = o;
}

__global__ void cast_w(const float* __restrict__ w0, const float* __restrict__ w1,
                       const float* __restrict__ w2, const float* __restrict__ w3,
                       unsigned short* __restrict__ dst) {
    const float* srcs[4] = {w0, w1, w2, w3};
    int wsel = blockIdx.y;
    const float4* src = (const float4*)srcs[wsel];
    int i = blockIdx.x * blockDim.x + threadIdx.x;   // 0..262143
    float4 v = src[i];
    ushort4 o;
    o.x = f2bf(v.x); o.y = f2bf(v.y); o.z = f2bf(v.z); o.w = f2bf(v.w);
    ((ushort4*)(dst + (size_t)wsel * 1048576))[i] = o;
}

// ---------------- T5 bias table: bias_tab[h][delta+2047], pre-multiplied by log2(e) ----
__global__ void bias_table(const float* __restrict__ rel_emb, float* __restrict__ bias_tab) {
    int idx = blockIdx.x * blockDim.x + threadIdx.x;
    if (idx >= NHEADS * 4095) return;
    int h = idx / 4095;
    int rp = (idx % 4095) - 2047;           // delta = mem - ctx
    int bucket = rp > 0 ? 16 : 0;
    int arp = rp < 0 ? -rp : rp;
    if (arp < 8) {
        bucket += arp;
    } else {
        float f = logf((float)arp / 7.0f) * (8.0f / logf(128.0f / 7.0f));
        int rl = 7 + (int)f;                // trunc == floor (f>0)
        bucket += rl < 15 ? rl : 15;
    }
    bias_tab[idx] = rel_emb[bucket * NHEADS + h] * 1.4426950408889634f;
}

// ---------------- GEMM: C[M,N] = A[M,K] * B[N,K]^T  (bf16 in, fp32 acc) -------------
// MODE 4: merged QKV.  B = [Wq;Wk;Wv] (3072x1024).  out = Q base; K at +8M, Vt at +16M.
//         Q scaled by 0.125*log2e; Q/K head-split [B,NH,T,HS]; V transposed [B,NH,HS,T].
// MODE 3: plain fp32 [M,1024] (output projection)
template<int MODE>
__global__ __launch_bounds__(256, 2) void gemm_bt(
    const unsigned short* __restrict__ A,
    const unsigned short* __restrict__ Bw,
    void* __restrict__ out)
{
    constexpr int K = 1024;
    __shared__ unsigned short As[128 * 64];
    __shared__ unsigned short Bs[128 * 64];

    const int tid  = threadIdx.x;
    const int wave = tid >> 6;
    const int lane = tid & 63;
    const int quad = lane >> 4;
    const int l16  = lane & 15;
    const int wm   = wave >> 1;
    const int wn   = wave & 1;
    const int bn   = blockIdx.x;
    const int bm   = blockIdx.y;

    const int r_in = lane >> 3;              // 0..7
    const int lc   = (lane & 7) ^ r_in;      // swizzled 16B chunk

    f32x4 acc[4][4];
    #pragma unroll
    for (int m = 0; m < 4; ++m)
        #pragma unroll
        for (int n = 0; n < 4; ++n)
            acc[m][n] = f32x4{0.f, 0.f, 0.f, 0.f};

    const long a_row0 = (long)bm * 128;
    const long b_row0 = (long)bn * 128;

    for (int kt = 0; kt < K / 64; ++kt) {
        __syncthreads();
        const int k0 = kt * 64 + lc * 8;
        #pragma unroll
        for (int c = 0; c < 4; ++c) {
            int cc = wave * 4 + c;
            int r  = cc * 8 + r_in;
            gld_lds16(A  + (a_row0 + r) * K + k0, &As[cc * 512]);
            gld_lds16(Bw + (b_row0 + r) * K + k0, &Bs[cc * 512]);
        }
        __syncthreads();

        bf16x8 af[4][2], bf[4][2];
        #pragma unroll
        for (int m = 0; m < 4; ++m)
            #pragma unroll
            for (int ks = 0; ks < 2; ++ks) {
                int r  = wm * 64 + m * 16 + l16;
                int pc = (ks * 4 + quad) ^ (r & 7);
                af[m][ks] = ld8(&As[r * 64 + pc * 8]);
            }
        #pragma unroll
        for (int n = 0; n < 4; ++n)
            #pragma unroll
            for (int ks = 0; ks < 2; ++ks) {
                int r  = wn * 64 + n * 16 + l16;
                int pc = (ks * 4 + quad) ^ (r & 7);
                bf[n][ks] = ld8(&Bs[r * 64 + pc * 8]);
            }
        #pragma unroll
        for (int ks = 0; ks < 2; ++ks)
            #pragma unroll
            for (int m = 0; m < 4; ++m)
                #pragma unroll
                for (int n = 0; n < 4; ++n)
                    acc[m][n] = __builtin_amdgcn_mfma_f32_16x16x32_bf16(
                        af[m][ks], bf[n][ks], acc[m][n], 0, 0, 0);
    }

    // epilogue: C/D layout col = lane&15, row = quad*4 + reg
    const int which = (MODE == 4) ? (bn >> 3) : 0;   // block-uniform: 0=Q 1=K 2=V
    #pragma unroll
    for (int m = 0; m < 4; ++m) {
        int row = bm * 128 + wm * 64 + m * 16 + quad * 4;
        #pragma unroll
        for (int n = 0; n < 4; ++n) {
            int col = bn * 128 + wn * 64 + n * 16 + l16;
            if (MODE == 3) {
                float* O = (float*)out;
                #pragma unroll
                for (int r = 0; r < 4; ++r)
                    O[(long)(row + r) * 1024 + col] = acc[m][n][r];
            } else {
                int cl = col & 1023;
                int h = cl >> 6, hs = cl & 63;
                int b = row >> 11, t = row & 2047;
                unsigned short* O = (unsigned short*)out + (size_t)which * 8388608;
                if (which == 2) {
                    ushort4 pk;
                    pk.x = f2bf(acc[m][n][0]); pk.y = f2bf(acc[m][n][1]);
                    pk.z = f2bf(acc[m][n][2]); pk.w = f2bf(acc[m][n][3]);
                    *(ushort4*)&O[(long)((b * 16 + h) * 64 + hs) * 2048 + t] = pk;
                } else {
                    #pragma unroll
                    for (int r = 0; r < 4; ++r) {
                        float v = acc[m][n][r];
                        if (which == 0) v *= 0.125f * 1.4426950408889634f;  // 1/sqrt(64)*log2e
                        O[(long)((b * 16 + h) * 2048 + (t + r)) * 64 + hs] = f2bf(v);
                    }
                }
            }
        }
    }
}

// ---------------- flash attention v4: swapped operands, no P round-trip --------------
// St = K*Q^T (C-layout: col=q, row=token) -> exp2 -> short4 == B-frag of 16x16x16 MFMA
// O^T = V^T * P accumulated (row=hs, col=q); LDS transpose once in epilogue.
// LDS: Ks 8K + Vs 8K + Bb 9.2K (loop) aliased with Es 36K (epilogue).
__global__ __launch_bounds__(256, 2) void attn(
    const unsigned short* __restrict__ Q,    // [B,NH,T,HS] bf16, pre-scaled by 0.125*log2e
    const unsigned short* __restrict__ Kb,   // [B,NH,T,HS] bf16
    const unsigned short* __restrict__ Vt,   // [B,NH,HS,T] bf16
    const float* __restrict__ bias_tab,      // [NH][4095], *log2e
    unsigned short* __restrict__ AO)         // [B,T,D] bf16
{
    __shared__ __align__(16) char smem[36864];
    unsigned short* Ks = (unsigned short*)smem;            // 8 KB  (64 tok x 64 hs)
    unsigned short* Vs = (unsigned short*)(smem + 8192);   // 8 KB  (64 hs x 64 tok)
    float*          Bb = (float*)(smem + 16384);           // 9212 B bias window

    const int tid  = threadIdx.x;
    const int wave = tid >> 6;
    const int lane = tid & 63;
    const int quad = lane >> 4;
    const int l16  = lane & 15;

    const int bh = blockIdx.y;          // b*16 + h
    const int b  = bh >> 4, h = bh & 15;
    const int q0 = blockIdx.x * 256;

    const unsigned short* Qg = Q  + (long)bh * T_SEQ * HSZ;
    const unsigned short* Kg = Kb + (long)bh * T_SEQ * HSZ;
    const unsigned short* Vg = Vt + (long)bh * HSZ * T_SEQ;

    // stage bias window: Bb[i] = bias(delta = i - 255 - q0), i in [0,2303)
    {
        const float* bt = bias_tab + h * 4095 + (1792 - q0);
        for (int i = tid; i < 2303; i += 256) Bb[i] = bt[i];
    }

    // Q fragments (B-operand of 16x16x32: lane holds q=l16, k=quad*8+j)
    bf16x8 qf[4][2];
    #pragma unroll
    for (int nt = 0; nt < 4; ++nt)
        #pragma unroll
        for (int ks = 0; ks < 2; ++ks) {
            int t = q0 + wave * 64 + nt * 16 + l16;
            qf[nt][ks] = ld8(&Qg[(long)t * 64 + ks * 32 + quad * 8]);
        }

    f32x4 o[4][4];    // O^T: o[mo][nt], row=hs=mo*16+quad*4+r, col=q=nt*16+l16
    float li[4];
    #pragma unroll
    for (int mo = 0; mo < 4; ++mo)
        #pragma unroll
        for (int nt = 0; nt < 4; ++nt) o[mo][nt] = f32x4{0.f, 0.f, 0.f, 0.f};
    #pragma unroll
    for (int nt = 0; nt < 4; ++nt) li[nt] = 0.0f;

    __syncthreads();   // bias window ready
    const float cneg = Bb[0];      // bias for delta <= -128 (bucket 15) region
    const float cpos = Bb[2302];   // bias for delta >= +128 (bucket 31) region

    const int r_in = lane >> 3;
    const int lc   = (lane & 7) ^ r_in;

    for (int kt = 0; kt < T_SEQ / 64; ++kt) {
        __syncthreads();   // prev tile reads done before overwrite
        #pragma unroll
        for (int c = 0; c < 2; ++c) {
            int cc = wave * 2 + c;
            int r  = cc * 8 + r_in;
            gld_lds16(Kg + (long)(kt * 64 + r) * 64 + lc * 8, &Ks[cc * 512]);
            gld_lds16(Vg + (long)r * T_SEQ + kt * 64 + lc * 8, &Vs[cc * 512]);
        }
        __syncthreads();   // tiles ready

        // T5 saturation: tile-uniform bias when the whole delta range is saturated
        const int lo = kt * 64 - q0 - 255;       // min delta this (block, kt)
        const int hi = kt * 64 + 63 - q0;        // max delta
        const bool outband = (lo >= 128) || (hi <= -128);
        const float cb = (lo >= 128) ? cpos : cneg;

        // ---- St = K Q^T, exp2, pack into PV B-fragments ----
        short4v pfrag[4][4];   // [token-chunk][q-tile]
        #pragma unroll
        for (int mt = 0; mt < 4; ++mt) {
            int rk = mt * 16 + l16;              // token row in Ks
            bf16x8 kf0 = ld8(&Ks[rk * 64 + ((quad)     ^ (rk & 7)) * 8]);
            bf16x8 kf1 = ld8(&Ks[rk * 64 + ((4 + quad) ^ (rk & 7)) * 8]);
            #pragma unroll
            for (int nt = 0; nt < 4; ++nt) {
                f32x4 s = f32x4{0.f, 0.f, 0.f, 0.f};
                s = __builtin_amdgcn_mfma_f32_16x16x32_bf16(kf0, qf[nt][0], s, 0, 0, 0);
                s = __builtin_amdgcn_mfma_f32_16x16x32_bf16(kf1, qf[nt][1], s, 0, 0, 0);
                float p[4];
                if (outband) {
                    #pragma unroll
                    for (int r = 0; r < 4; ++r)
                        p[r] = __builtin_exp2f(s[r] + cb);
                } else {
                    int i0 = kt * 64 + mt * 16 + quad * 4
                           - wave * 64 - nt * 16 - l16 + 255;
                    #pragma unroll
                    for (int r = 0; r < 4; ++r)
                        p[r] = __builtin_exp2f(s[r] + Bb[i0 + r]);
                }
                li[nt] += (p[0] + p[1]) + (p[2] + p[3]);
                uint2 pk = {pk2bf(p[0], p[1]), pk2bf(p[2], p[3])};
                pfrag[mt][nt] = __builtin_bit_cast(short4v, pk);
            }
        }

        // ---- O^T += V^T P  (A = V^T frag: lane holds hs=l16(+mo*16), k=quad*4+j) ----
        #pragma unroll
        for (int mo = 0; mo < 4; ++mo) {
            int rv = mo * 16 + l16;              // hs row in Vs
            #pragma unroll
            for (int kc = 0; kc < 4; ++kc) {
                int ch = ((kc * 2 + (quad >> 1)) ^ (rv & 7));
                short4v vf = *(const short4v*)&Vs[rv * 64 + ch * 8 + (quad & 1) * 4];
                #pragma unroll
                for (int nt = 0; nt < 4; ++nt)
                    o[mo][nt] = mfma16_bf16(vf, pfrag[kc][nt], o[mo][nt]);
            }
        }
    }

    // li: queries live in lanes; reduce across the 4 quads only
    #pragma unroll
    for (int nt = 0; nt < 4; ++nt) {
        li[nt] += __shfl_xor(li[nt], 16);
        li[nt] += __shfl_xor(li[nt], 32);
    }
    float inv[4];
    #pragma unroll
    for (int nt = 0; nt < 4; ++nt) inv[nt] = 1.0f / li[nt];

    // epilogue: transpose O^T -> O through LDS (Es aliases Ks/Vs/Bb), coalesced stores
    __syncthreads();   // all waves done reading Ks/Vs/Bb
    unsigned short* Ew = (unsigned short*)smem + wave * 4608;   // 64 rows x 72 stride
    #pragma unroll
    for (int mo = 0; mo < 4; ++mo)
        #pragma unroll
        for (int nt = 0; nt < 4; ++nt) {
            uint2 pk = {pk2bf(o[mo][nt][0] * inv[nt], o[mo][nt][1] * inv[nt]),
                        pk2bf(o[mo][nt][2] * inv[nt], o[mo][nt][3] * inv[nt])};
            *(uint2*)&Ew[(nt * 16 + l16) * 72 + mo * 16 + quad * 4] = pk;
        }
    asm volatile("s_waitcnt lgkmcnt(0)" ::: "memory");  // wave-private write->read

    #pragma unroll
    for (int rr = 0; rr < 8; ++rr) {
        int row   = rr * 8 + (lane >> 3);   // local q
        int chunk = lane & 7;
        uint4 v = *(const uint4*)&Ew[row * 72 + chunk * 8];
        *(uint4*)&AO[(long)(b * T_SEQ + q0 + wave * 64 + row) * D_MODEL + h * 64 + chunk * 8] = v;
    }
}

// ---------------- launch ----------------
extern "C" void kernel_launch(void* const* d_in, const int* in_sizes, int n_in,
                              void* d_out, int out_size, void* d_ws, size_t ws_size,
                              hipStream_t stream) {
    const float* x   = (const float*)d_in[0];
    const float* wq  = (const float*)d_in[1];
    const float* wk  = (const float*)d_in[2];
    const float* wv  = (const float*)d_in[3];
    const float* wo  = (const float*)d_in[4];
    const float* rel = (const float*)d_in[5];

    char* ws = (char*)d_ws;
    unsigned short* Xbf = (unsigned short*)(ws);                      // 16 MiB (reused as AO)
    unsigned short* Wbf = (unsigned short*)(ws + (16l << 20));        // 8 MiB (Wq,Wk,Wv,Wo)
    unsigned short* Qb  = (unsigned short*)(ws + (24l << 20));        // Q,K,Vt contiguous 48 MiB
    float*          btb = (float*)(ws + (72l << 20));                 // 256 KiB

    cast_x<<<8192, 256, 0, stream>>>(x, Xbf, 2097152);
    cast_w<<<dim3(1024, 4), 256, 0, stream>>>(wq, wk, wv, wo, Wbf);
    bias_table<<<256, 256, 0, stream>>>(rel, btb);

    // merged QKV projection: C[8192, 3072] vs concatenated [Wq;Wk;Wv]
    gemm_bt<4><<<dim3(24, 64), 256, 0, stream>>>(Xbf, Wbf, Qb);

    unsigned short* Kbf = Qb + 8388608;
    unsigned short* Vtb = Qb + 16777216;
    unsigned short* AO  = Xbf;  // X dead after the projection
    attn<<<dim3(8, 64), 256, 0, stream>>>(Qb, Kbf, Vtb, btb, AO);

    gemm_bt<3><<<dim3(8, 64), 256, 0, stream>>>(AO, Wbf + 3 * 1048576, d_out);
}

// Round 5
// 294.948 us; speedup vs baseline: 1.1406x; 1.1406x over previous
//
#include <hip/hip_runtime.h>

#define T_SEQ 2048
#define D_MODEL 1024
#define NHEADS 16
#define HSZ 64
#define BATCH 4

typedef __bf16 bf16x8 __attribute__((ext_vector_type(8)));
typedef __bf16 bf16x4 __attribute__((ext_vector_type(4)));
typedef short short4v __attribute__((ext_vector_type(4)));
typedef float f32x4 __attribute__((ext_vector_type(4)));

__device__ __forceinline__ unsigned short f2bf(float f) {
    unsigned int u = __builtin_bit_cast(unsigned int, f);
    u += 0x7fff + ((u >> 16) & 1);   // RNE
    return (unsigned short)(u >> 16);
}

// pack two fp32 -> two bf16 (RNE) in one reg
__device__ __forceinline__ unsigned int pk2bf(float a, float b) {
#if __has_builtin(__builtin_amdgcn_cvt_pk_bf16_f32)
    typedef __bf16 bf16x2_t __attribute__((ext_vector_type(2)));
    bf16x2_t v = __builtin_amdgcn_cvt_pk_bf16_f32(a, b);
    return __builtin_bit_cast(unsigned int, v);
#else
    return (unsigned int)f2bf(a) | ((unsigned int)f2bf(b) << 16);
#endif
}

// raw v_exp_f32 (domain bounded; denormal flush acceptable)
__device__ __forceinline__ float fexp2(float x) {
#if __has_builtin(__builtin_amdgcn_exp2f)
    return __builtin_amdgcn_exp2f(x);
#else
    return __builtin_exp2f(x);
#endif
}

// K=16 bf16 MFMA: D[m][n] += sum_k A[m][k]B[k][n]; per-lane k = quad*4+j
__device__ __forceinline__ f32x4 mfma16_bf16(short4v a, short4v b, f32x4 c) {
#if __has_builtin(__builtin_amdgcn_mfma_f32_16x16x16_bf16)
    return __builtin_amdgcn_mfma_f32_16x16x16_bf16(
        __builtin_bit_cast(bf16x4, a), __builtin_bit_cast(bf16x4, b), c, 0, 0, 0);
#elif __has_builtin(__builtin_amdgcn_mfma_f32_16x16x16bf16_1k)
    return __builtin_amdgcn_mfma_f32_16x16x16bf16_1k(a, b, c, 0, 0, 0);
#else
    f32x4 d;
    asm volatile("v_mfma_f32_16x16x16_bf16 %0, %1, %2, %3"
                 : "=v"(d) : "v"(a), "v"(b), "v"(c));
    return d;
#endif
}

__device__ __forceinline__ void gld_lds16(const void* g, void* lds) {
    __builtin_amdgcn_global_load_lds(
        (const __attribute__((address_space(1))) unsigned int*)g,
        (__attribute__((address_space(3))) unsigned int*)lds, 16, 0, 0);
}

__device__ __forceinline__ bf16x8 ld8(const unsigned short* p) {
    return *(const bf16x8*)p;
}

// ---------------- casts ----------------
__global__ void cast_x(const float* __restrict__ src, unsigned short* __restrict__ dst, int n4) {
    int i = blockIdx.x * blockDim.x + threadIdx.x;
    if (i >= n4) return;
    float4 v = ((const float4*)src)[i];
    ushort4 o;
    o.x = f2bf(v.x); o.y = f2bf(v.y); o.z = f2bf(v.z); o.w = f2bf(v.w);
    ((ushort4*)dst)[i] = o;
}

__global__ void cast_w(const float* __restrict__ w0, const float* __restrict__ w1,
                       const float* __restrict__ w2, const float* __restrict__ w3,
                       unsigned short* __restrict__ dst) {
    const float* srcs[4] = {w0, w1, w2, w3};
    int wsel = blockIdx.y;
    const float4* src = (const float4*)srcs[wsel];
    int i = blockIdx.x * blockDim.x + threadIdx.x;   // 0..262143
    float4 v = src[i];
    ushort4 o;
    o.x = f2bf(v.x); o.y = f2bf(v.y); o.z = f2bf(v.z); o.w = f2bf(v.w);
    ((ushort4*)(dst + (size_t)wsel * 1048576))[i] = o;
}

// ---------------- T5 bias table: bias_tab[h][delta+2047], pre-multiplied by log2(e) ----
__global__ void bias_table(const float* __restrict__ rel_emb, float* __restrict__ bias_tab) {
    int idx = blockIdx.x * blockDim.x + threadIdx.x;
    if (idx >= NHEADS * 4095) return;
    int h = idx / 4095;
    int rp = (idx % 4095) - 2047;           // delta = mem - ctx
    int bucket = rp > 0 ? 16 : 0;
    int arp = rp < 0 ? -rp : rp;
    if (arp < 8) {
        bucket += arp;
    } else {
        float f = logf((float)arp / 7.0f) * (8.0f / logf(128.0f / 7.0f));
        int rl = 7 + (int)f;                // trunc == floor (f>0)
        bucket += rl < 15 ? rl : 15;
    }
    bias_tab[idx] = rel_emb[bucket * NHEADS + h] * 1.4426950408889634f;
}

// ---------------- GEMM: C[M,N] = A[M,K] * B[N,K]^T  (bf16 in, fp32 acc) -------------
// MODE 4: merged QKV.  B = [Wq;Wk;Wv] (3072x1024).  out = Q base; K at +8M, Vt at +16M.
//         Q scaled by 0.125*log2e; Q/K head-split [B,NH,T,HS]; V transposed [B,NH,HS,T].
// MODE 3: plain fp32 [M,1024] (output projection)
template<int MODE>
__global__ __launch_bounds__(256, 2) void gemm_bt(
    const unsigned short* __restrict__ A,
    const unsigned short* __restrict__ Bw,
    void* __restrict__ out)
{
    constexpr int K = 1024;
    __shared__ unsigned short As[128 * 64];
    __shared__ unsigned short Bs[128 * 64];

    const int tid  = threadIdx.x;
    const int wave = tid >> 6;
    const int lane = tid & 63;
    const int quad = lane >> 4;
    const int l16  = lane & 15;
    const int wm   = wave >> 1;
    const int wn   = wave & 1;
    const int bn   = blockIdx.x;
    const int bm   = blockIdx.y;

    const int r_in = lane >> 3;              // 0..7
    const int lc   = (lane & 7) ^ r_in;      // swizzled 16B chunk

    f32x4 acc[4][4];
    #pragma unroll
    for (int m = 0; m < 4; ++m)
        #pragma unroll
        for (int n = 0; n < 4; ++n)
            acc[m][n] = f32x4{0.f, 0.f, 0.f, 0.f};

    const long a_row0 = (long)bm * 128;
    const long b_row0 = (long)bn * 128;

    for (int kt = 0; kt < K / 64; ++kt) {
        __syncthreads();
        const int k0 = kt * 64 + lc * 8;
        #pragma unroll
        for (int c = 0; c < 4; ++c) {
            int cc = wave * 4 + c;
            int r  = cc * 8 + r_in;
            gld_lds16(A  + (a_row0 + r) * K + k0, &As[cc * 512]);
            gld_lds16(Bw + (b_row0 + r) * K + k0, &Bs[cc * 512]);
        }
        __syncthreads();

        bf16x8 af[4][2], bf[4][2];
        #pragma unroll
        for (int m = 0; m < 4; ++m)
            #pragma unroll
            for (int ks = 0; ks < 2; ++ks) {
                int r  = wm * 64 + m * 16 + l16;
                int pc = (ks * 4 + quad) ^ (r & 7);
                af[m][ks] = ld8(&As[r * 64 + pc * 8]);
            }
        #pragma unroll
        for (int n = 0; n < 4; ++n)
            #pragma unroll
            for (int ks = 0; ks < 2; ++ks) {
                int r  = wn * 64 + n * 16 + l16;
                int pc = (ks * 4 + quad) ^ (r & 7);
                bf[n][ks] = ld8(&Bs[r * 64 + pc * 8]);
            }
        #pragma unroll
        for (int ks = 0; ks < 2; ++ks)
            #pragma unroll
            for (int m = 0; m < 4; ++m)
                #pragma unroll
                for (int n = 0; n < 4; ++n)
                    acc[m][n] = __builtin_amdgcn_mfma_f32_16x16x32_bf16(
                        af[m][ks], bf[n][ks], acc[m][n], 0, 0, 0);
    }

    // epilogue: C/D layout col = lane&15, row = quad*4 + reg
    const int which = (MODE == 4) ? (bn >> 3) : 0;   // block-uniform: 0=Q 1=K 2=V
    #pragma unroll
    for (int m = 0; m < 4; ++m) {
        int row = bm * 128 + wm * 64 + m * 16 + quad * 4;
        #pragma unroll
        for (int n = 0; n < 4; ++n) {
            int col = bn * 128 + wn * 64 + n * 16 + l16;
            if (MODE == 3) {
                float* O = (float*)out;
                #pragma unroll
                for (int r = 0; r < 4; ++r)
                    O[(long)(row + r) * 1024 + col] = acc[m][n][r];
            } else {
                int cl = col & 1023;
                int h = cl >> 6, hs = cl & 63;
                int b = row >> 11, t = row & 2047;
                unsigned short* O = (unsigned short*)out + (size_t)which * 8388608;
                if (which == 2) {
                    ushort4 pk;
                    pk.x = f2bf(acc[m][n][0]); pk.y = f2bf(acc[m][n][1]);
                    pk.z = f2bf(acc[m][n][2]); pk.w = f2bf(acc[m][n][3]);
                    *(ushort4*)&O[(long)((b * 16 + h) * 64 + hs) * 2048 + t] = pk;
                } else {
                    #pragma unroll
                    for (int r = 0; r < 4; ++r) {
                        float v = acc[m][n][r];
                        if (which == 0) v *= 0.125f * 1.4426950408889634f;  // 1/sqrt(64)*log2e
                        O[(long)((b * 16 + h) * 2048 + (t + r)) * 64 + hs] = f2bf(v);
                    }
                }
            }
        }
    }
}

// ---------------- flash attention v5 --------------------------------------------------
// Double-buffered K/V staging (1 barrier/kt). St = K*Q^T; pfrag (St C-layout) feeds PV
// directly as the A-operand of 16x16x16 MFMA -> O accumulated untransposed. Bias folded
// into MFMA C-init. LDS: Ks dbuf 16K + Vs dbuf 16K + Bb 9.2K = 41.2 KB.
__global__ __launch_bounds__(256, 2) void attn(
    const unsigned short* __restrict__ Q,    // [B,NH,T,HS] bf16, pre-scaled by 0.125*log2e
    const unsigned short* __restrict__ Kb,   // [B,NH,T,HS] bf16
    const unsigned short* __restrict__ Vt,   // [B,NH,HS,T] bf16
    const float* __restrict__ bias_tab,      // [NH][4095], *log2e
    unsigned short* __restrict__ AO)         // [B,T,D] bf16
{
    __shared__ __align__(16) char smem[41984];
    unsigned short* KsB = (unsigned short*)smem;             // 2 x 8 KB (64 tok x 64 hs)
    unsigned short* VsB = (unsigned short*)(smem + 16384);   // 2 x 8 KB (64 hs x 64 tok)
    float*          Bb  = (float*)(smem + 32768);            // 2303 floats bias window

    const int tid  = threadIdx.x;
    const int wave = tid >> 6;
    const int lane = tid & 63;
    const int quad = lane >> 4;
    const int l16  = lane & 15;

    const int bh = blockIdx.y;          // b*16 + h
    const int b  = bh >> 4, h = bh & 15;
    const int q0 = blockIdx.x * 256;

    const unsigned short* Qg = Q  + (long)bh * T_SEQ * HSZ;
    const unsigned short* Kg = Kb + (long)bh * T_SEQ * HSZ;
    const unsigned short* Vg = Vt + (long)bh * HSZ * T_SEQ;

    const int r_in = lane >> 3;
    const int lc   = (lane & 7) ^ r_in;

    // prefetch tile 0 into buffer 0
    {
        #pragma unroll
        for (int c = 0; c < 2; ++c) {
            int cc = wave * 2 + c;
            int r  = cc * 8 + r_in;
            gld_lds16(Kg + (long)r * 64 + lc * 8, &KsB[cc * 512]);
            gld_lds16(Vg + (long)r * T_SEQ + lc * 8, &VsB[cc * 512]);
        }
    }

    // stage bias window: Bb[i] = bias(delta = i - 255 - q0), i in [0,2303)
    {
        const float* bt = bias_tab + h * 4095 + (1792 - q0);
        for (int i = tid; i < 2303; i += 256) Bb[i] = bt[i];
    }

    // Q fragments (B-operand of 16x16x32: lane holds q=l16, k=quad*8+j)
    bf16x8 qf[4][2];
    #pragma unroll
    for (int nt = 0; nt < 4; ++nt)
        #pragma unroll
        for (int ks = 0; ks < 2; ++ks) {
            int t = q0 + wave * 64 + nt * 16 + l16;
            qf[nt][ks] = ld8(&Qg[(long)t * 64 + ks * 32 + quad * 8]);
        }

    f32x4 o[4][4];    // O: o[nq][nh], row=q=nq*16+quad*4+r, col=hs=nh*16+l16
    float li[4];
    #pragma unroll
    for (int nq = 0; nq < 4; ++nq)
        #pragma unroll
        for (int nh = 0; nh < 4; ++nh) o[nq][nh] = f32x4{0.f, 0.f, 0.f, 0.f};
    #pragma unroll
    for (int nq = 0; nq < 4; ++nq) li[nq] = 0.0f;

    float cneg, cpos;
    {
        const float* bt = bias_tab + h * 4095;
        cneg = bt[0];      // delta <= -2047: saturated negative bucket
        cpos = bt[4094];   // delta >= +2047: saturated positive bucket
    }

    for (int kt = 0; kt < T_SEQ / 64; ++kt) {
        const int cur = kt & 1;
        __syncthreads();   // vmcnt(0): cur buffer staged; all prev-buffer reads done

        if (kt + 1 < T_SEQ / 64) {          // prefetch next tile into other buffer
            unsigned short* Kn = KsB + (cur ^ 1) * 4096;
            unsigned short* Vn = VsB + (cur ^ 1) * 4096;
            #pragma unroll
            for (int c = 0; c < 2; ++c) {
                int cc = wave * 2 + c;
                int r  = cc * 8 + r_in;
                gld_lds16(Kg + (long)((kt + 1) * 64 + r) * 64 + lc * 8, &Kn[cc * 512]);
                gld_lds16(Vg + (long)r * T_SEQ + (kt + 1) * 64 + lc * 8, &Vn[cc * 512]);
            }
        }

        const unsigned short* Ks = KsB + cur * 4096;
        const unsigned short* Vs = VsB + cur * 4096;

        // T5 saturation: tile-uniform bias when whole delta range is saturated
        const int lo = kt * 64 - q0 - 255;       // min delta this (block, kt)
        const int hi = kt * 64 + 63 - q0;        // max delta
        const bool outband = (lo >= 128) || (hi <= -128);
        const float cb = (lo >= 128) ? cpos : cneg;
        const f32x4 cbv = {cb, cb, cb, cb};

        // ---- St = K Q^T (+bias via C-init), exp2, pack into PV A-fragments ----
        short4v pfrag[4][4];   // [token-chunk kc][q-tile nq]; A-layout m=q=l16, k=quad*4+j
        #pragma unroll
        for (int kc = 0; kc < 4; ++kc) {
            int rk = kc * 16 + l16;              // token row in Ks
            bf16x8 kf0 = ld8(&Ks[rk * 64 + ((quad)     ^ (rk & 7)) * 8]);
            bf16x8 kf1 = ld8(&Ks[rk * 64 + ((4 + quad) ^ (rk & 7)) * 8]);
            #pragma unroll
            for (int nq = 0; nq < 4; ++nq) {
                f32x4 c0;
                if (outband) {
                    c0 = cbv;
                } else {
                    int i0 = kt * 64 + kc * 16 + quad * 4
                           - wave * 64 - nq * 16 - l16 + 255;
                    c0 = f32x4{Bb[i0], Bb[i0 + 1], Bb[i0 + 2], Bb[i0 + 3]};
                }
                f32x4 s = __builtin_amdgcn_mfma_f32_16x16x32_bf16(kf0, qf[nq][0], c0, 0, 0, 0);
                s = __builtin_amdgcn_mfma_f32_16x16x32_bf16(kf1, qf[nq][1], s, 0, 0, 0);
                float p[4];
                #pragma unroll
                for (int r = 0; r < 4; ++r) p[r] = fexp2(s[r]);
                li[nq] += (p[0] + p[1]) + (p[2] + p[3]);
                uint2 pk = {pk2bf(p[0], p[1]), pk2bf(p[2], p[3])};
                pfrag[kc][nq] = __builtin_bit_cast(short4v, pk);
            }
        }

        // ---- O += P V: A = pfrag (regs), B = V^T rows (n=hs=l16, k=tok=quad*4+j) ----
        #pragma unroll
        for (int kc = 0; kc < 4; ++kc) {
            short4v vf[4];
            #pragma unroll
            for (int nh = 0; nh < 4; ++nh) {
                int rv = nh * 16 + l16;          // hs row in Vs
                int ch = (kc * 2 + (quad >> 1)) ^ (rv & 7);
                vf[nh] = *(const short4v*)&Vs[rv * 64 + ch * 8 + (quad & 1) * 4];
            }
            #pragma unroll
            for (int nq = 0; nq < 4; ++nq)
                #pragma unroll
                for (int nh = 0; nh < 4; ++nh)
                    o[nq][nh] = mfma16_bf16(pfrag[kc][nq], vf[nh], o[nq][nh]);
        }
    }

    // li: q lives at lane l16; reduce across the 4 quads
    #pragma unroll
    for (int nq = 0; nq < 4; ++nq) {
        li[nq] += __shfl_xor(li[nq], 16);
        li[nq] += __shfl_xor(li[nq], 32);
    }
    float inv[4];
    #pragma unroll
    for (int nq = 0; nq < 4; ++nq) inv[nq] = 1.0f / li[nq];

    // epilogue: O rows are q=quad*4+r but inv lives at lane l16=q -> shfl redistribute
    #pragma unroll
    for (int nq = 0; nq < 4; ++nq) {
        float iv[4];
        #pragma unroll
        for (int r = 0; r < 4; ++r) iv[r] = __shfl(inv[nq], quad * 4 + r);
        int qrow = q0 + wave * 64 + nq * 16 + quad * 4;
        #pragma unroll
        for (int r = 0; r < 4; ++r)
            #pragma unroll
            for (int nh = 0; nh < 4; ++nh)
                AO[(long)(b * T_SEQ + qrow + r) * D_MODEL + h * 64 + nh * 16 + l16] =
                    f2bf(o[nq][nh][r] * iv[r]);
    }
}

// ---------------- launch ----------------
extern "C" void kernel_launch(void* const* d_in, const int* in_sizes, int n_in,
                              void* d_out, int out_size, void* d_ws, size_t ws_size,
                              hipStream_t stream) {
    const float* x   = (const float*)d_in[0];
    const float* wq  = (const float*)d_in[1];
    const float* wk  = (const float*)d_in[2];
    const float* wv  = (const float*)d_in[3];
    const float* wo  = (const float*)d_in[4];
    const float* rel = (const float*)d_in[5];

    char* ws = (char*)d_ws;
    unsigned short* Xbf = (unsigned short*)(ws);                      // 16 MiB (reused as AO)
    unsigned short* Wbf = (unsigned short*)(ws + (16l << 20));        // 8 MiB (Wq,Wk,Wv,Wo)
    unsigned short* Qb  = (unsigned short*)(ws + (24l << 20));        // Q,K,Vt contiguous 48 MiB
    float*          btb = (float*)(ws + (72l << 20));                 // 256 KiB

    cast_x<<<8192, 256, 0, stream>>>(x, Xbf, 2097152);
    cast_w<<<dim3(1024, 4), 256, 0, stream>>>(wq, wk, wv, wo, Wbf);
    bias_table<<<256, 256, 0, stream>>>(rel, btb);

    // merged QKV projection: C[8192, 3072] vs concatenated [Wq;Wk;Wv]
    gemm_bt<4><<<dim3(24, 64), 256, 0, stream>>>(Xbf, Wbf, Qb);

    unsigned short* Kbf = Qb + 8388608;
    unsigned short* Vtb = Qb + 16777216;
    unsigned short* AO  = Xbf;  // X dead after the projection
    attn<<<dim3(8, 64), 256, 0, stream>>>(Qb, Kbf, Vtb, btb, AO);

    gemm_bt<3><<<dim3(8, 64), 256, 0, stream>>>(AO, Wbf + 3 * 1048576, d_out);
}

// Round 6
// 268.006 us; speedup vs baseline: 1.2553x; 1.1005x over previous
//
#include <hip/hip_runtime.h>

#define T_SEQ 2048
#define D_MODEL 1024
#define NHEADS 16
#define HSZ 64
#define BATCH 4

typedef __bf16 bf16x8 __attribute__((ext_vector_type(8)));
typedef __bf16 bf16x4 __attribute__((ext_vector_type(4)));
typedef short short4v __attribute__((ext_vector_type(4)));
typedef float f32x4 __attribute__((ext_vector_type(4)));

__device__ __forceinline__ unsigned short f2bf(float f) {
    unsigned int u = __builtin_bit_cast(unsigned int, f);
    u += 0x7fff + ((u >> 16) & 1);   // RNE
    return (unsigned short)(u >> 16);
}

// pack two fp32 -> two bf16 (RNE) in one reg
__device__ __forceinline__ unsigned int pk2bf(float a, float b) {
#if __has_builtin(__builtin_amdgcn_cvt_pk_bf16_f32)
    typedef __bf16 bf16x2_t __attribute__((ext_vector_type(2)));
    bf16x2_t v = __builtin_amdgcn_cvt_pk_bf16_f32(a, b);
    return __builtin_bit_cast(unsigned int, v);
#else
    return (unsigned int)f2bf(a) | ((unsigned int)f2bf(b) << 16);
#endif
}

// raw v_exp_f32 (domain bounded; denormal flush acceptable)
__device__ __forceinline__ float fexp2(float x) {
#if __has_builtin(__builtin_amdgcn_exp2f)
    return __builtin_amdgcn_exp2f(x);
#else
    return __builtin_exp2f(x);
#endif
}

// K=16 bf16 MFMA: D[m][n] += sum_k A[m][k]B[k][n]; per-lane k = quad*4+j
__device__ __forceinline__ f32x4 mfma16_bf16(short4v a, short4v b, f32x4 c) {
#if __has_builtin(__builtin_amdgcn_mfma_f32_16x16x16_bf16)
    return __builtin_amdgcn_mfma_f32_16x16x16_bf16(
        __builtin_bit_cast(bf16x4, a), __builtin_bit_cast(bf16x4, b), c, 0, 0, 0);
#elif __has_builtin(__builtin_amdgcn_mfma_f32_16x16x16bf16_1k)
    return __builtin_amdgcn_mfma_f32_16x16x16bf16_1k(a, b, c, 0, 0, 0);
#else
    f32x4 d;
    asm volatile("v_mfma_f32_16x16x16_bf16 %0, %1, %2, %3"
                 : "=v"(d) : "v"(a), "v"(b), "v"(c));
    return d;
#endif
}

__device__ __forceinline__ void gld_lds16(const void* g, void* lds) {
    __builtin_amdgcn_global_load_lds(
        (const __attribute__((address_space(1))) unsigned int*)g,
        (__attribute__((address_space(3))) unsigned int*)lds, 16, 0, 0);
}

__device__ __forceinline__ bf16x8 ld8(const unsigned short* p) {
    return *(const bf16x8*)p;
}

// ---------------- fused prep: cast X, cast W, build bias table ----------------------
// grid: [0,8192) cast_x | [8192,12288) cast_w | [12288,12544) bias_table
__global__ void prep(const float* __restrict__ x,
                     const float* __restrict__ w0, const float* __restrict__ w1,
                     const float* __restrict__ w2, const float* __restrict__ w3,
                     const float* __restrict__ rel,
                     unsigned short* __restrict__ Xbf,
                     unsigned short* __restrict__ Wbf,
                     float* __restrict__ bias_tab) {
    int bid = blockIdx.x;
    int tid = threadIdx.x;
    if (bid < 8192) {
        int i = bid * 256 + tid;            // 2097152 float4s
        float4 v = ((const float4*)x)[i];
        ushort4 o;
        o.x = f2bf(v.x); o.y = f2bf(v.y); o.z = f2bf(v.z); o.w = f2bf(v.w);
        ((ushort4*)Xbf)[i] = o;
    } else if (bid < 12288) {
        int wsel = (bid - 8192) >> 10;
        const float* srcs[4] = {w0, w1, w2, w3};
        int i = ((bid - 8192) & 1023) * 256 + tid;   // 262144 float4s per W
        float4 v = ((const float4*)srcs[wsel])[i];
        ushort4 o;
        o.x = f2bf(v.x); o.y = f2bf(v.y); o.z = f2bf(v.z); o.w = f2bf(v.w);
        ((ushort4*)(Wbf + (size_t)wsel * 1048576))[i] = o;
    } else {
        int idx = (bid - 12288) * 256 + tid;
        if (idx >= NHEADS * 4095) return;
        int h = idx / 4095;
        int rp = (idx % 4095) - 2047;       // delta = mem - ctx
        int bucket = rp > 0 ? 16 : 0;
        int arp = rp < 0 ? -rp : rp;
        if (arp < 8) {
            bucket += arp;
        } else {
            float f = logf((float)arp / 7.0f) * (8.0f / logf(128.0f / 7.0f));
            int rl = 7 + (int)f;            // trunc == floor (f>0)
            bucket += rl < 15 ? rl : 15;
        }
        bias_tab[idx] = rel[bucket * NHEADS + h] * 1.4426950408889634f;
    }
}

// ---------------- GEMM: C[M,N] = A[M,K] * B[N,K]^T  (bf16 in, fp32 acc) -------------
// MODE 4: merged QKV.  B = [Wq;Wk;Wv] (3072x1024).  out = Q base; K at +8M, Vt at +16M.
//         Q scaled by 0.125*log2e; Q/K head-split [B,NH,T,HS] (LDS-transpose epilogue,
//         vectorized dwordx4 stores); V transposed [B,NH,HS,T] (r-packed ushort4).
// MODE 3: plain fp32 [M,1024] (output projection)
template<int MODE>
__global__ __launch_bounds__(256, 2) void gemm_bt(
    const unsigned short* __restrict__ A,
    const unsigned short* __restrict__ Bw,
    void* __restrict__ out)
{
    constexpr int K = 1024;
    __shared__ __align__(16) char smem[36864];
    unsigned short* As = (unsigned short*)smem;             // 128x64 shorts, 16 KB
    unsigned short* Bs = (unsigned short*)(smem + 16384);   // 128x64 shorts, 16 KB

    const int tid  = threadIdx.x;
    const int wave = tid >> 6;
    const int lane = tid & 63;
    const int quad = lane >> 4;
    const int l16  = lane & 15;
    const int wm   = wave >> 1;
    const int wn   = wave & 1;
    const int bn   = blockIdx.x;
    const int bm   = blockIdx.y;

    const int r_in = lane >> 3;              // 0..7
    const int lc   = (lane & 7) ^ r_in;      // swizzled 16B chunk

    f32x4 acc[4][4];
    #pragma unroll
    for (int m = 0; m < 4; ++m)
        #pragma unroll
        for (int n = 0; n < 4; ++n)
            acc[m][n] = f32x4{0.f, 0.f, 0.f, 0.f};

    const long a_row0 = (long)bm * 128;
    const long b_row0 = (long)bn * 128;

    for (int kt = 0; kt < K / 64; ++kt) {
        __syncthreads();
        const int k0 = kt * 64 + lc * 8;
        #pragma unroll
        for (int c = 0; c < 4; ++c) {
            int cc = wave * 4 + c;
            int r  = cc * 8 + r_in;
            gld_lds16(A  + (a_row0 + r) * K + k0, &As[cc * 512]);
            gld_lds16(Bw + (b_row0 + r) * K + k0, &Bs[cc * 512]);
        }
        __syncthreads();

        bf16x8 af[4][2], bf[4][2];
        #pragma unroll
        for (int m = 0; m < 4; ++m)
            #pragma unroll
            for (int ks = 0; ks < 2; ++ks) {
                int r  = wm * 64 + m * 16 + l16;
                int pc = (ks * 4 + quad) ^ (r & 7);
                af[m][ks] = ld8(&As[r * 64 + pc * 8]);
            }
        #pragma unroll
        for (int n = 0; n < 4; ++n)
            #pragma unroll
            for (int ks = 0; ks < 2; ++ks) {
                int r  = wn * 64 + n * 16 + l16;
                int pc = (ks * 4 + quad) ^ (r & 7);
                bf[n][ks] = ld8(&Bs[r * 64 + pc * 8]);
            }
        #pragma unroll
        for (int ks = 0; ks < 2; ++ks)
            #pragma unroll
            for (int m = 0; m < 4; ++m)
                #pragma unroll
                for (int n = 0; n < 4; ++n)
                    acc[m][n] = __builtin_amdgcn_mfma_f32_16x16x32_bf16(
                        af[m][ks], bf[n][ks], acc[m][n], 0, 0, 0);
    }

    // epilogue: C/D layout col = lane&15, row = quad*4 + reg
    const int which = (MODE == 4) ? (bn >> 3) : 0;   // block-uniform: 0=Q 1=K 2=V
    if (MODE == 3) {
        float* O = (float*)out;
        #pragma unroll
        for (int m = 0; m < 4; ++m) {
            int row = bm * 128 + wm * 64 + m * 16 + quad * 4;
            #pragma unroll
            for (int n = 0; n < 4; ++n) {
                int col = bn * 128 + wn * 64 + n * 16 + l16;
                #pragma unroll
                for (int r = 0; r < 4; ++r)
                    O[(long)(row + r) * 1024 + col] = acc[m][n][r];
            }
        }
    } else if (which == 2) {
        // V: r-packed ushort4 direct to [B,NH,HS,T]
        unsigned short* O = (unsigned short*)out + (size_t)2 * 8388608;
        #pragma unroll
        for (int m = 0; m < 4; ++m) {
            int row = bm * 128 + wm * 64 + m * 16 + quad * 4;
            int b = row >> 11, t = row & 2047;
            #pragma unroll
            for (int n = 0; n < 4; ++n) {
                int cl = (bn * 128 + wn * 64 + n * 16 + l16) & 1023;
                int h = cl >> 6, hs = cl & 63;
                ushort4 pk;
                pk.x = f2bf(acc[m][n][0]); pk.y = f2bf(acc[m][n][1]);
                pk.z = f2bf(acc[m][n][2]); pk.w = f2bf(acc[m][n][3]);
                *(ushort4*)&O[(long)((b * 16 + h) * 64 + hs) * 2048 + t] = pk;
            }
        }
    } else {
        // Q/K: per-wave LDS transpose -> contiguous dwordx4 stores to [B,NH,T,HS].
        // Wave's 64-col group == one (which, head); 64x64 tile is 8 KB contiguous out.
        __syncthreads();   // all waves done with As/Bs k-loop reads
        unsigned short* Ew = (unsigned short*)smem + wave * 4608;   // 64 x 72-stride
        const float qs = (which == 0) ? 0.125f * 1.4426950408889634f : 1.0f;
        #pragma unroll
        for (int m = 0; m < 4; ++m)
            #pragma unroll
            for (int n = 0; n < 4; ++n)
                #pragma unroll
                for (int r = 0; r < 4; ++r)
                    Ew[(m * 16 + quad * 4 + r) * 72 + n * 16 + l16] =
                        f2bf(acc[m][n][r] * qs);
        asm volatile("s_waitcnt lgkmcnt(0)" ::: "memory");  // wave-private write->read

        const int cl0 = (bn * 128 + wn * 64) & 1023;
        const int h   = cl0 >> 6;
        const int gr0 = bm * 128 + wm * 64;
        const int b   = gr0 >> 11, t0 = gr0 & 2047;
        unsigned short* O = (unsigned short*)out + (size_t)which * 8388608
                          + ((size_t)(b * 16 + h) * 2048 + t0) * 64;
        #pragma unroll
        for (int rr = 0; rr < 8; ++rr) {
            int row   = rr * 8 + (lane >> 3);
            int chunk = lane & 7;
            uint4 v = *(const uint4*)&Ew[row * 72 + chunk * 8];
            *(uint4*)&O[(size_t)row * 64 + chunk * 8] = v;
        }
    }
}

// ---------------- flash attention v5 (unchanged from R5) -----------------------------
// Double-buffered K/V staging (1 barrier/kt). St = K*Q^T; pfrag (St C-layout) feeds PV
// directly as the A-operand of 16x16x16 MFMA -> O accumulated untransposed. Bias folded
// into MFMA C-init. LDS: Ks dbuf 16K + Vs dbuf 16K + Bb 9.2K = 41.2 KB.
__global__ __launch_bounds__(256, 2) void attn(
    const unsigned short* __restrict__ Q,    // [B,NH,T,HS] bf16, pre-scaled by 0.125*log2e
    const unsigned short* __restrict__ Kb,   // [B,NH,T,HS] bf16
    const unsigned short* __restrict__ Vt,   // [B,NH,HS,T] bf16
    const float* __restrict__ bias_tab,      // [NH][4095], *log2e
    unsigned short* __restrict__ AO)         // [B,T,D] bf16
{
    __shared__ __align__(16) char smem[41984];
    unsigned short* KsB = (unsigned short*)smem;             // 2 x 8 KB (64 tok x 64 hs)
    unsigned short* VsB = (unsigned short*)(smem + 16384);   // 2 x 8 KB (64 hs x 64 tok)
    float*          Bb  = (float*)(smem + 32768);            // 2303 floats bias window

    const int tid  = threadIdx.x;
    const int wave = tid >> 6;
    const int lane = tid & 63;
    const int quad = lane >> 4;
    const int l16  = lane & 15;

    const int bh = blockIdx.y;          // b*16 + h
    const int b  = bh >> 4, h = bh & 15;
    const int q0 = blockIdx.x * 256;

    const unsigned short* Qg = Q  + (long)bh * T_SEQ * HSZ;
    const unsigned short* Kg = Kb + (long)bh * T_SEQ * HSZ;
    const unsigned short* Vg = Vt + (long)bh * HSZ * T_SEQ;

    const int r_in = lane >> 3;
    const int lc   = (lane & 7) ^ r_in;

    // prefetch tile 0 into buffer 0
    {
        #pragma unroll
        for (int c = 0; c < 2; ++c) {
            int cc = wave * 2 + c;
            int r  = cc * 8 + r_in;
            gld_lds16(Kg + (long)r * 64 + lc * 8, &KsB[cc * 512]);
            gld_lds16(Vg + (long)r * T_SEQ + lc * 8, &VsB[cc * 512]);
        }
    }

    // stage bias window: Bb[i] = bias(delta = i - 255 - q0), i in [0,2303)
    {
        const float* bt = bias_tab + h * 4095 + (1792 - q0);
        for (int i = tid; i < 2303; i += 256) Bb[i] = bt[i];
    }

    // Q fragments (B-operand of 16x16x32: lane holds q=l16, k=quad*8+j)
    bf16x8 qf[4][2];
    #pragma unroll
    for (int nt = 0; nt < 4; ++nt)
        #pragma unroll
        for (int ks = 0; ks < 2; ++ks) {
            int t = q0 + wave * 64 + nt * 16 + l16;
            qf[nt][ks] = ld8(&Qg[(long)t * 64 + ks * 32 + quad * 8]);
        }

    f32x4 o[4][4];    // O: o[nq][nh], row=q=nq*16+quad*4+r, col=hs=nh*16+l16
    float li[4];
    #pragma unroll
    for (int nq = 0; nq < 4; ++nq)
        #pragma unroll
        for (int nh = 0; nh < 4; ++nh) o[nq][nh] = f32x4{0.f, 0.f, 0.f, 0.f};
    #pragma unroll
    for (int nq = 0; nq < 4; ++nq) li[nq] = 0.0f;

    float cneg, cpos;
    {
        const float* bt = bias_tab + h * 4095;
        cneg = bt[0];      // delta <= -2047: saturated negative bucket
        cpos = bt[4094];   // delta >= +2047: saturated positive bucket
    }

    for (int kt = 0; kt < T_SEQ / 64; ++kt) {
        const int cur = kt & 1;
        __syncthreads();   // vmcnt(0): cur buffer staged; all prev-buffer reads done

        if (kt + 1 < T_SEQ / 64) {          // prefetch next tile into other buffer
            unsigned short* Kn = KsB + (cur ^ 1) * 4096;
            unsigned short* Vn = VsB + (cur ^ 1) * 4096;
            #pragma unroll
            for (int c = 0; c < 2; ++c) {
                int cc = wave * 2 + c;
                int r  = cc * 8 + r_in;
                gld_lds16(Kg + (long)((kt + 1) * 64 + r) * 64 + lc * 8, &Kn[cc * 512]);
                gld_lds16(Vg + (long)r * T_SEQ + (kt + 1) * 64 + lc * 8, &Vn[cc * 512]);
            }
        }

        const unsigned short* Ks = KsB + cur * 4096;
        const unsigned short* Vs = VsB + cur * 4096;

        // T5 saturation: tile-uniform bias when whole delta range is saturated
        const int lo = kt * 64 - q0 - 255;       // min delta this (block, kt)
        const int hi = kt * 64 + 63 - q0;        // max delta
        const bool outband = (lo >= 128) || (hi <= -128);
        const float cb = (lo >= 128) ? cpos : cneg;
        const f32x4 cbv = {cb, cb, cb, cb};

        // ---- St = K Q^T (+bias via C-init), exp2, pack into PV A-fragments ----
        short4v pfrag[4][4];   // [token-chunk kc][q-tile nq]; A-layout m=q=l16, k=quad*4+j
        #pragma unroll
        for (int kc = 0; kc < 4; ++kc) {
            int rk = kc * 16 + l16;              // token row in Ks
            bf16x8 kf0 = ld8(&Ks[rk * 64 + ((quad)     ^ (rk & 7)) * 8]);
            bf16x8 kf1 = ld8(&Ks[rk * 64 + ((4 + quad) ^ (rk & 7)) * 8]);
            #pragma unroll
            for (int nq = 0; nq < 4; ++nq) {
                f32x4 c0;
                if (outband) {
                    c0 = cbv;
                } else {
                    int i0 = kt * 64 + kc * 16 + quad * 4
                           - wave * 64 - nq * 16 - l16 + 255;
                    c0 = f32x4{Bb[i0], Bb[i0 + 1], Bb[i0 + 2], Bb[i0 + 3]};
                }
                f32x4 s = __builtin_amdgcn_mfma_f32_16x16x32_bf16(kf0, qf[nq][0], c0, 0, 0, 0);
                s = __builtin_amdgcn_mfma_f32_16x16x32_bf16(kf1, qf[nq][1], s, 0, 0, 0);
                float p[4];
                #pragma unroll
                for (int r = 0; r < 4; ++r) p[r] = fexp2(s[r]);
                li[nq] += (p[0] + p[1]) + (p[2] + p[3]);
                uint2 pk = {pk2bf(p[0], p[1]), pk2bf(p[2], p[3])};
                pfrag[kc][nq] = __builtin_bit_cast(short4v, pk);
            }
        }

        // ---- O += P V: A = pfrag (regs), B = V^T rows (n=hs=l16, k=tok=quad*4+j) ----
        #pragma unroll
        for (int kc = 0; kc < 4; ++kc) {
            short4v vf[4];
            #pragma unroll
            for (int nh = 0; nh < 4; ++nh) {
                int rv = nh * 16 + l16;          // hs row in Vs
                int ch = (kc * 2 + (quad >> 1)) ^ (rv & 7);
                vf[nh] = *(const short4v*)&Vs[rv * 64 + ch * 8 + (quad & 1) * 4];
            }
            #pragma unroll
            for (int nq = 0; nq < 4; ++nq)
                #pragma unroll
                for (int nh = 0; nh < 4; ++nh)
                    o[nq][nh] = mfma16_bf16(pfrag[kc][nq], vf[nh], o[nq][nh]);
        }
    }

    // li: q lives at lane l16; reduce across the 4 quads
    #pragma unroll
    for (int nq = 0; nq < 4; ++nq) {
        li[nq] += __shfl_xor(li[nq], 16);
        li[nq] += __shfl_xor(li[nq], 32);
    }
    float inv[4];
    #pragma unroll
    for (int nq = 0; nq < 4; ++nq) inv[nq] = 1.0f / li[nq];

    // epilogue: O rows are q=quad*4+r but inv lives at lane l16=q -> shfl redistribute
    #pragma unroll
    for (int nq = 0; nq < 4; ++nq) {
        float iv[4];
        #pragma unroll
        for (int r = 0; r < 4; ++r) iv[r] = __shfl(inv[nq], quad * 4 + r);
        int qrow = q0 + wave * 64 + nq * 16 + quad * 4;
        #pragma unroll
        for (int r = 0; r < 4; ++r)
            #pragma unroll
            for (int nh = 0; nh < 4; ++nh)
                AO[(long)(b * T_SEQ + qrow + r) * D_MODEL + h * 64 + nh * 16 + l16] =
                    f2bf(o[nq][nh][r] * iv[r]);
    }
}

// ---------------- launch ----------------
extern "C" void kernel_launch(void* const* d_in, const int* in_sizes, int n_in,
                              void* d_out, int out_size, void* d_ws, size_t ws_size,
                              hipStream_t stream) {
    const float* x   = (const float*)d_in[0];
    const float* wq  = (const float*)d_in[1];
    const float* wk  = (const float*)d_in[2];
    const float* wv  = (const float*)d_in[3];
    const float* wo  = (const float*)d_in[4];
    const float* rel = (const float*)d_in[5];

    char* ws = (char*)d_ws;
    unsigned short* Xbf = (unsigned short*)(ws);                      // 16 MiB (reused as AO)
    unsigned short* Wbf = (unsigned short*)(ws + (16l << 20));        // 8 MiB (Wq,Wk,Wv,Wo)
    unsigned short* Qb  = (unsigned short*)(ws + (24l << 20));        // Q,K,Vt contiguous 48 MiB
    float*          btb = (float*)(ws + (72l << 20));                 // 256 KiB

    prep<<<12544, 256, 0, stream>>>(x, wq, wk, wv, wo, rel, Xbf, Wbf, btb);

    // merged QKV projection: C[8192, 3072] vs concatenated [Wq;Wk;Wv]
    gemm_bt<4><<<dim3(24, 64), 256, 0, stream>>>(Xbf, Wbf, Qb);

    unsigned short* Kbf = Qb + 8388608;
    unsigned short* Vtb = Qb + 16777216;
    unsigned short* AO  = Xbf;  // X dead after the projection
    attn<<<dim3(8, 64), 256, 0, stream>>>(Qb, Kbf, Vtb, btb, AO);

    gemm_bt<3><<<dim3(8, 64), 256, 0, stream>>>(AO, Wbf + 3 * 1048576, d_out);
}